// Round 8
// baseline (73.065 us; speedup 1.0000x reference)
//
#include <hip/hip_runtime.h>
#include <math.h>

#define BB 2
#define NN 512
#define IND 64
#define HH 8
#define DD 8
#define CC 64          // H*D channels
#define QUADS 16       // channel quads (CC/4)
#define JSLOTS 32      // parallel j slots per block (512 threads / 16 quads)
#define NWAVES 8

typedef float f4 __attribute__((ext_vector_type(4)));

// ---------------- Kernel 1: Q,K,V projections ----------------
__global__ __launch_bounds__(64)
void qkv_kernel(const float* __restrict__ h,
                const float* __restrict__ WQ,
                const float* __restrict__ WK,
                const float* __restrict__ WV,
                float* __restrict__ Qw,
                float* __restrict__ Kw,
                float* __restrict__ Vw) {
    int bi = blockIdx.x;          // b*N + i
    int c  = threadIdx.x;         // 0..63
    __shared__ float hrow[IND];
    hrow[c] = h[bi * IND + c];
    __syncthreads();
    float aq = 0.f, ak = 0.f, av = 0.f;
#pragma unroll
    for (int k = 0; k < IND; ++k) {
        float hv = hrow[k];
        aq += hv * WQ[c * IND + k];
        ak += hv * WK[c * IND + k];
        av += hv * WV[c * IND + k];
    }
    Qw[bi * CC + c] = aq;
    Kw[bi * CC + c] = ak * 0.35355339059327376f;  // 8^-0.5
    Vw[bi * CC + c] = av;
}

// ---------------- Kernel 2: fused masked softmax-attention ----------------
// One block per (b,i), 512 threads = 8 waves. q = tid&15 (channel quad),
// jg = tid>>4 (32 parallel j slots). Valid-j compaction keeps streamed
// footprint ~214 MB (< 256 MB L3) -> warm-replay L3 residency.
// __launch_bounds__(512, 8): 8 waves/EU -> 4 blocks/CU -> 100% occupancy cap
// (the (512,4) variant silently capped at 2 blocks/CU = 50%). VGPR 36 < 64 cap.
__global__ __launch_bounds__(512, 8)
void attn_kernel(const float* __restrict__ e_att,
                 const float* __restrict__ e_value,
                 const int*   __restrict__ mask,
                 const float* __restrict__ Qw,
                 const float* __restrict__ Kw,
                 const float* __restrict__ Vw,
                 float* __restrict__ out) {
    int bi  = blockIdx.x;          // b*N + i
    int b   = bi >> 9;             // / N
    int tid = threadIdx.x;
    int q   = tid & 15;            // channel quad: channels 4q..4q+3
    int jg  = tid >> 4;            // j slot 0..31
    int wv  = tid >> 6;            // wave 0..7
    int hh  = q >> 1;              // head of this quad

    __shared__ float  Qrow[CC];
    __shared__ float  qk_s[NN * HH];          // [j][h], 16 KB
    __shared__ int    jlist[NN];              // compacted valid j, 2 KB
    __shared__ int    wtot[NWAVES], woff[NWAVES];
    __shared__ int    nvalid_s;
    __shared__ float4 wred_l[NWAVES][QUADS];  // per-wave partial l, 2 KB
    __shared__ float4 wred_a[NWAVES][QUADS];  // per-wave partial a, 2 KB

    if (tid < CC) Qrow[tid] = Qw[bi * CC + tid];
    jlist[tid] = 0;                // pad entries point at row 0 (weight 0)

    // --- mask compaction: thread tid owns j = tid ---
    int valid = mask[(size_t)bi * NN + tid] != 0;
    unsigned long long ball = __ballot(valid);
    int lane = tid & 63;
    int rank = __popcll(ball & ((1ull << lane) - 1ull));
    if (lane == 0) wtot[wv] = __popcll(ball);
    __syncthreads();
    if (tid == 0) {
        int s = 0;
#pragma unroll
        for (int w = 0; w < NWAVES; ++w) { woff[w] = s; s += wtot[w]; }
        nvalid_s = s;
    }
    __syncthreads();
    if (valid) jlist[woff[wv] + rank] = tid;

    const float* Kb = Kw + (size_t)b * NN * CC;
    const float* Vb = Vw + (size_t)b * NN * CC;

    // qk[j][h] = sum_d Qrow[h*8+d] * Kb[j*64 + h*8 + d]
#pragma unroll
    for (int e = tid; e < NN * HH; e += 512) {
        int j = e >> 3, h = e & 7;
        const float* kr = Kb + (size_t)j * CC + h * 8;
        float k0[4], k1[4];
        *(float4*)k0 = *(const float4*)(kr);
        *(float4*)k1 = *(const float4*)(kr + 4);
        float s = 0.f;
#pragma unroll
        for (int d = 0; d < 4; ++d) s += Qrow[h * 8 + d] * k0[d];
#pragma unroll
        for (int d = 0; d < 4; ++d) s += Qrow[h * 8 + 4 + d] * k1[d];
        qk_s[e] = s;
    }
    __syncthreads();   // covers jlist, nvalid_s, qk_s

    const f4* ea_row = (const f4*)(e_att   + (size_t)bi * NN * CC) + q;
    const f4* ev_row = (const f4*)(e_value + (size_t)bi * NN * CC) + q;
    const f4* v_col  = (const f4*)Vb + q;

    int nvalid = nvalid_s;
    int nblk   = (nvalid + 127) >> 7;   // each blk = 4 unrolled iters x 32 slots

    float l[4] = {0.f, 0.f, 0.f, 0.f};
    float a[4] = {0.f, 0.f, 0.f, 0.f};

    for (int blk = 0; blk < nblk; ++blk) {
#pragma unroll
        for (int u = 0; u < 4; ++u) {
            int idx = blk * 128 + u * JSLOTS + jg;    // <= 511 always
            int j   = jlist[idx];
            float w = (idx < nvalid) ? 1.f : 0.f;
            f4 ea4 = ea_row[(size_t)j * QUADS];
            f4 ev4 = ev_row[(size_t)j * QUADS];
            f4 vv4 = v_col [(size_t)j * QUADS];
            float qk = qk_s[j * HH + hh];
#pragma unroll
            for (int cc = 0; cc < 4; ++cc) {
                float s = fminf(qk + ea4[cc], 30.f);  // overflow insurance
                float p = w * __expf(s);
                l[cc] += p;
                a[cc] += p * (vv4[cc] + ev4[cc]);
            }
        }
    }

    // intra-wave sum over the 4 j-slots in this wave (lanes xor 16, 32)
#pragma unroll
    for (int off = 16; off <= 32; off <<= 1) {
#pragma unroll
        for (int cc = 0; cc < 4; ++cc) {
            l[cc] += __shfl_xor(l[cc], off, 64);
            a[cc] += __shfl_xor(a[cc], off, 64);
        }
    }
    if ((tid & 63) < QUADS) {
        wred_l[wv][q] = make_float4(l[0], l[1], l[2], l[3]);
        wred_a[wv][q] = make_float4(a[0], a[1], a[2], a[3]);
    }
    __syncthreads();

    // cross-wave sum; threads 0..63 each own one channel
    if (tid < CC) {
        int cq = tid >> 2, sub = tid & 3;
        float L = 0.f, A = 0.f;
#pragma unroll
        for (int w = 0; w < NWAVES; ++w) {
            L += ((const float*)&wred_l[w][cq])[sub];
            A += ((const float*)&wred_a[w][cq])[sub];
        }
        out[(size_t)bi * CC + tid] = (L > 0.f) ? (A / L) : 0.f;
    }
}

extern "C" void kernel_launch(void* const* d_in, const int* in_sizes, int n_in,
                              void* d_out, int out_size, void* d_ws, size_t ws_size,
                              hipStream_t stream) {
    const float* h       = (const float*)d_in[0];
    const float* e_att   = (const float*)d_in[1];
    const float* e_value = (const float*)d_in[2];
    const int*   mask    = (const int*)  d_in[3];
    const float* WQ      = (const float*)d_in[4];
    const float* WK      = (const float*)d_in[5];
    const float* WV      = (const float*)d_in[6];
    float* out = (float*)d_out;

    float* Qw = (float*)d_ws;
    float* Kw = Qw + (size_t)BB * NN * CC;
    float* Vw = Kw + (size_t)BB * NN * CC;

    qkv_kernel<<<BB * NN, 64, 0, stream>>>(h, WQ, WK, WV, Qw, Kw, Vw);
    attn_kernel<<<BB * NN, 512, 0, stream>>>(e_att, e_value, mask, Qw, Kw, Vw, out);
}

// Round 9
// 49.567 us; speedup vs baseline: 1.4740x; 1.4740x over previous
//
#include <hip/hip_runtime.h>
#include <math.h>

#define BB 2
#define NN 512
#define IND 64
#define HH 8
#define DD 8
#define CC 64          // H*D channels
#define QUADS 16       // channel quads (CC/4)
#define JSLOTS 32      // parallel j slots per block (512 threads / 16 quads)
#define NWAVES 8

typedef float f4 __attribute__((ext_vector_type(4)));

// ---------------- Kernel 1: Q,K,V projections ----------------
__global__ __launch_bounds__(64)
void qkv_kernel(const float* __restrict__ h,
                const float* __restrict__ WQ,
                const float* __restrict__ WK,
                const float* __restrict__ WV,
                float* __restrict__ Qw,
                float* __restrict__ Kw,
                float* __restrict__ Vw) {
    int bi = blockIdx.x;          // b*N + i
    int c  = threadIdx.x;         // 0..63
    __shared__ float hrow[IND];
    hrow[c] = h[bi * IND + c];
    __syncthreads();
    float aq = 0.f, ak = 0.f, av = 0.f;
#pragma unroll
    for (int k = 0; k < IND; ++k) {
        float hv = hrow[k];
        aq += hv * WQ[c * IND + k];
        ak += hv * WK[c * IND + k];
        av += hv * WV[c * IND + k];
    }
    Qw[bi * CC + c] = aq;
    Kw[bi * CC + c] = ak * 0.35355339059327376f;  // 8^-0.5
    Vw[bi * CC + c] = av;
}

// ---------------- Kernel 2: fused masked softmax-attention ----------------
// One block per (b,i), 512 threads = 8 waves, __launch_bounds__(512,4)
// (2 blocks/CU, occ ~52% -- empirically the best point; higher occ raised
// FETCH_SIZE and regressed). Valid-j compaction keeps the streamed footprint
// ~214 MB < 256 MB L3.
// Hot loop: 4-iteration load BATCH with named scalars -- LDS index reads
// first, then 12 back-to-back dwordx4 issues, then consume. 4x the per-wave
// in-flight bytes of the R6 version (VGPR 36 -> ~80).
__global__ __launch_bounds__(512, 4)
void attn_kernel(const float* __restrict__ e_att,
                 const float* __restrict__ e_value,
                 const int*   __restrict__ mask,
                 const float* __restrict__ Qw,
                 const float* __restrict__ Kw,
                 const float* __restrict__ Vw,
                 float* __restrict__ out) {
    int bi  = blockIdx.x;          // b*N + i
    int b   = bi >> 9;             // / N
    int tid = threadIdx.x;
    int q   = tid & 15;            // channel quad: channels 4q..4q+3
    int jg  = tid >> 4;            // j slot 0..31
    int wv  = tid >> 6;            // wave 0..7
    int hh  = q >> 1;              // head of this quad

    __shared__ float  Qrow[CC];
    __shared__ float  qk_s[NN * HH];          // [j][h], 16 KB
    __shared__ int    jlist[NN];              // compacted valid j, 2 KB
    __shared__ int    wtot[NWAVES], woff[NWAVES];
    __shared__ int    nvalid_s;
    __shared__ float4 wred_l[NWAVES][QUADS];  // per-wave partial l, 2 KB
    __shared__ float4 wred_a[NWAVES][QUADS];  // per-wave partial a, 2 KB

    if (tid < CC) Qrow[tid] = Qw[bi * CC + tid];
    jlist[tid] = 0;                // pad entries point at row 0 (weight 0)

    // --- mask compaction: thread tid owns j = tid ---
    int valid = mask[(size_t)bi * NN + tid] != 0;
    unsigned long long ball = __ballot(valid);
    int lane = tid & 63;
    int rank = __popcll(ball & ((1ull << lane) - 1ull));
    if (lane == 0) wtot[wv] = __popcll(ball);
    __syncthreads();
    if (tid == 0) {
        int s = 0;
#pragma unroll
        for (int w = 0; w < NWAVES; ++w) { woff[w] = s; s += wtot[w]; }
        nvalid_s = s;
    }
    __syncthreads();
    if (valid) jlist[woff[wv] + rank] = tid;

    const float* Kb = Kw + (size_t)b * NN * CC;
    const float* Vb = Vw + (size_t)b * NN * CC;

    // qk[j][h] = sum_d Qrow[h*8+d] * Kb[j*64 + h*8 + d]
#pragma unroll
    for (int e = tid; e < NN * HH; e += 512) {
        int j = e >> 3, h = e & 7;
        const float* kr = Kb + (size_t)j * CC + h * 8;
        float k0[4], k1[4];
        *(float4*)k0 = *(const float4*)(kr);
        *(float4*)k1 = *(const float4*)(kr + 4);
        float s = 0.f;
#pragma unroll
        for (int d = 0; d < 4; ++d) s += Qrow[h * 8 + d] * k0[d];
#pragma unroll
        for (int d = 0; d < 4; ++d) s += Qrow[h * 8 + 4 + d] * k1[d];
        qk_s[e] = s;
    }
    __syncthreads();   // covers jlist, nvalid_s, qk_s

    const f4* ea_row = (const f4*)(e_att   + (size_t)bi * NN * CC) + q;
    const f4* ev_row = (const f4*)(e_value + (size_t)bi * NN * CC) + q;
    const f4* v_col  = (const f4*)Vb + q;

    int nvalid = nvalid_s;
    int nblk   = (nvalid + 127) >> 7;   // each blk = 4 batched iters x 32 slots

    float l[4] = {0.f, 0.f, 0.f, 0.f};
    float a[4] = {0.f, 0.f, 0.f, 0.f};

    for (int blk = 0; blk < nblk; ++blk) {
        int base = blk * 128 + jg;
        // --- phase 1: LDS index/qk reads for all 4 iterations ---
        int i0 = base, i1 = base + JSLOTS, i2 = base + 2 * JSLOTS, i3 = base + 3 * JSLOTS;
        int j0 = jlist[i0], j1 = jlist[i1], j2 = jlist[i2], j3 = jlist[i3];
        float w0 = (i0 < nvalid) ? 1.f : 0.f;
        float w1 = (i1 < nvalid) ? 1.f : 0.f;
        float w2 = (i2 < nvalid) ? 1.f : 0.f;
        float w3 = (i3 < nvalid) ? 1.f : 0.f;
        float qk0 = qk_s[j0 * HH + hh], qk1 = qk_s[j1 * HH + hh];
        float qk2 = qk_s[j2 * HH + hh], qk3 = qk_s[j3 * HH + hh];
        // --- phase 2: issue all 12 global loads back-to-back ---
        f4 ea0 = ea_row[(size_t)j0 * QUADS];
        f4 ev0 = ev_row[(size_t)j0 * QUADS];
        f4 vv0 = v_col [(size_t)j0 * QUADS];
        f4 ea1 = ea_row[(size_t)j1 * QUADS];
        f4 ev1 = ev_row[(size_t)j1 * QUADS];
        f4 vv1 = v_col [(size_t)j1 * QUADS];
        f4 ea2 = ea_row[(size_t)j2 * QUADS];
        f4 ev2 = ev_row[(size_t)j2 * QUADS];
        f4 vv2 = v_col [(size_t)j2 * QUADS];
        f4 ea3 = ea_row[(size_t)j3 * QUADS];
        f4 ev3 = ev_row[(size_t)j3 * QUADS];
        f4 vv3 = v_col [(size_t)j3 * QUADS];
        // --- phase 3: consume in issue order ---
#pragma unroll
        for (int cc = 0; cc < 4; ++cc) {
            float p = w0 * __expf(fminf(qk0 + ea0[cc], 30.f));
            l[cc] += p;
            a[cc] += p * (vv0[cc] + ev0[cc]);
        }
#pragma unroll
        for (int cc = 0; cc < 4; ++cc) {
            float p = w1 * __expf(fminf(qk1 + ea1[cc], 30.f));
            l[cc] += p;
            a[cc] += p * (vv1[cc] + ev1[cc]);
        }
#pragma unroll
        for (int cc = 0; cc < 4; ++cc) {
            float p = w2 * __expf(fminf(qk2 + ea2[cc], 30.f));
            l[cc] += p;
            a[cc] += p * (vv2[cc] + ev2[cc]);
        }
#pragma unroll
        for (int cc = 0; cc < 4; ++cc) {
            float p = w3 * __expf(fminf(qk3 + ea3[cc], 30.f));
            l[cc] += p;
            a[cc] += p * (vv3[cc] + ev3[cc]);
        }
    }

    // intra-wave sum over the 4 j-slots in this wave (lanes xor 16, 32)
#pragma unroll
    for (int off = 16; off <= 32; off <<= 1) {
#pragma unroll
        for (int cc = 0; cc < 4; ++cc) {
            l[cc] += __shfl_xor(l[cc], off, 64);
            a[cc] += __shfl_xor(a[cc], off, 64);
        }
    }
    if ((tid & 63) < QUADS) {
        wred_l[wv][q] = make_float4(l[0], l[1], l[2], l[3]);
        wred_a[wv][q] = make_float4(a[0], a[1], a[2], a[3]);
    }
    __syncthreads();

    // cross-wave sum; threads 0..63 each own one channel
    if (tid < CC) {
        int cq = tid >> 2, sub = tid & 3;
        float L = 0.f, A = 0.f;
#pragma unroll
        for (int w = 0; w < NWAVES; ++w) {
            L += ((const float*)&wred_l[w][cq])[sub];
            A += ((const float*)&wred_a[w][cq])[sub];
        }
        out[(size_t)bi * CC + tid] = (L > 0.f) ? (A / L) : 0.f;
    }
}

extern "C" void kernel_launch(void* const* d_in, const int* in_sizes, int n_in,
                              void* d_out, int out_size, void* d_ws, size_t ws_size,
                              hipStream_t stream) {
    const float* h       = (const float*)d_in[0];
    const float* e_att   = (const float*)d_in[1];
    const float* e_value = (const float*)d_in[2];
    const int*   mask    = (const int*)  d_in[3];
    const float* WQ      = (const float*)d_in[4];
    const float* WK      = (const float*)d_in[5];
    const float* WV      = (const float*)d_in[6];
    float* out = (float*)d_out;

    float* Qw = (float*)d_ws;
    float* Kw = Qw + (size_t)BB * NN * CC;
    float* Vw = Kw + (size_t)BB * NN * CC;

    qkv_kernel<<<BB * NN, 64, 0, stream>>>(h, WQ, WK, WV, Qw, Kw, Vw);
    attn_kernel<<<BB * NN, 512, 0, stream>>>(e_att, e_value, mask, Qw, Kw, Vw, out);
}